// Round 1
// baseline (2118.014 us; speedup 1.0000x reference)
//
#include <hip/hip_runtime.h>
#include <math.h>
#include <stdint.h>

#define H 16
#define Dm 1024
#define DH2 64
#define SLEN 8192
#define BATCH 2

typedef __attribute__((ext_vector_type(8))) short bf16x8;
typedef __attribute__((ext_vector_type(4))) float f32x4;
typedef __attribute__((ext_vector_type(4))) short short4v;

#define MFMA16(a,b,c) __builtin_amdgcn_mfma_f32_16x16x32_bf16(a,b,c,0,0,0)

static __device__ __forceinline__ short f2b(float f){
  unsigned u = __builtin_bit_cast(unsigned, f);
  u += 0x7fffu + ((u >> 16) & 1u);
  return (short)(u >> 16);
}

static __device__ __forceinline__ void gload16(const void* g, void* l){
  __builtin_amdgcn_global_load_lds((const __attribute__((address_space(1))) void*)g,
                                   (__attribute__((address_space(3))) void*)l, 16, 0, 0);
}

// ---------------- weight transpose: WT[n][k] = bf16(W[k][n]) ----------------
__global__ __launch_bounds__(256) void transpose_w_kernel(
    const float* __restrict__ Wq, const float* __restrict__ Wk,
    const float* __restrict__ Wv, const float* __restrict__ Wo,
    short* __restrict__ WqT, short* __restrict__ WkT,
    short* __restrict__ WvT, short* __restrict__ WoT)
{
  const float* W; short* WT;
  switch (blockIdx.z){
    case 0: W = Wq; WT = WqT; break;
    case 1: W = Wk; WT = WkT; break;
    case 2: W = Wv; WT = WvT; break;
    default: W = Wo; WT = WoT; break;
  }
  __shared__ float t[32][33];
  int tx = threadIdx.x & 31, ty = threadIdx.x >> 5;
  int x0 = blockIdx.x * 32, y0 = blockIdx.y * 32;
  for (int j = 0; j < 4; ++j){
    int r = ty + j * 8;
    t[r][tx] = W[(size_t)(y0 + r) * Dm + x0 + tx];
  }
  __syncthreads();
  for (int j = 0; j < 4; ++j){
    int r = ty + j * 8;
    WT[(size_t)(x0 + r) * Dm + y0 + tx] = f2b(t[tx][r]);
  }
}

// ---------------- QKV projection GEMM -------------------------------------
// C = A(f32)[16384x1024] @ W, W^T stored bf16 [n][k]. 128x128 tile, BK=64.
// z=0: Q (scaled 0.125) -> Qh[b][h][s][64]; z=1: K -> Kh same; z=2: V -> VhT[b][h][64][s]
__global__ __launch_bounds__(256) void proj_kernel(
    const float* __restrict__ Aq, const float* __restrict__ Ak, const float* __restrict__ Av,
    const short* __restrict__ WqT, const short* __restrict__ WkT, const short* __restrict__ WvT,
    const float* __restrict__ bq, const float* __restrict__ bk, const float* __restrict__ bv,
    short* __restrict__ Qh, short* __restrict__ Kh, short* __restrict__ VhT)
{
  const float* A; const short* WT; const float* bias;
  int z = blockIdx.z;
  if (z == 0){ A = Aq; WT = WqT; bias = bq; }
  else if (z == 1){ A = Ak; WT = WkT; bias = bk; }
  else { A = Av; WT = WvT; bias = bv; }

  __shared__ __align__(16) char smem[34816];
  short (*As)[64] = (short(*)[64])smem;        // [128][64]
  short* Bs = (short*)(smem + 16384);          // [128][64] linear (gload_lds dest)

  int tid = threadIdx.x;
  int lane = tid & 63, w = tid >> 6;
  int l15 = lane & 15, lh = lane >> 4;
  int wm = w >> 1, wn = w & 1;
  int m0 = blockIdx.x * 128, n0 = blockIdx.y * 128;

  f32x4 acc[4][4];
  for (int i = 0; i < 4; ++i)
    for (int j = 0; j < 4; ++j)
      acc[i][j] = (f32x4){0.f, 0.f, 0.f, 0.f};

  for (int ko = 0; ko < 16; ++ko){
    // A: f32 -> bf16 reg-staged
    for (int j = 0; j < 8; ++j){
      int idx = j * 256 + tid;            // 2048 float4 units
      int r = idx >> 4, c4 = idx & 15;
      float4 a = *(const float4*)(A + (size_t)(m0 + r) * Dm + ko * 64 + c4 * 4);
      short4v p; p[0] = f2b(a.x); p[1] = f2b(a.y); p[2] = f2b(a.z); p[3] = f2b(a.w);
      *(short4v*)&As[r][c4 * 4] = p;
    }
    // B: async global->LDS, 16 chunks of 1KB
    for (int j = 0; j < 4; ++j){
      int c = w * 4 + j;
      int row = c * 8 + (lane >> 3), seg = lane & 7;
      gload16(WT + (size_t)(n0 + row) * Dm + ko * 64 + seg * 8, Bs + c * 512);
    }
    __syncthreads();
    for (int kk = 0; kk < 2; ++kk){
      bf16x8 af[4];
      for (int i = 0; i < 4; ++i)
        af[i] = *(const bf16x8*)&As[wm * 64 + i * 16 + l15][kk * 32 + lh * 8];
      for (int jj = 0; jj < 4; ++jj){
        bf16x8 bfv = *(const bf16x8*)(Bs + (size_t)(wn * 64 + jj * 16 + l15) * 64 + kk * 32 + lh * 8);
        for (int i = 0; i < 4; ++i)
          acc[i][jj] = MFMA16(af[i], bfv, acc[i][jj]);
      }
    }
    __syncthreads();
  }

  if (z < 2){
    short* out = (z == 0) ? Qh : Kh;
    float scale = (z == 0) ? 0.125f : 1.0f;   // fold 1/sqrt(64) into Q
    for (int jj = 0; jj < 4; ++jj){
      int col = n0 + wn * 64 + jj * 16 + l15;
      float bb = bias[col];
      int h = col >> 6, d = col & 63;
      for (int i = 0; i < 4; ++i)
        for (int r = 0; r < 4; ++r){
          int row = m0 + wm * 64 + i * 16 + lh * 4 + r;
          int b = row >> 13, s = row & 8191;
          out[(((size_t)b * H + h) * SLEN + s) * DH2 + d] = f2b((acc[i][jj][r] + bb) * scale);
        }
    }
  } else {
    // V: transpose in LDS, write VhT coalesced along s
    short (*Ct)[136] = (short(*)[136])smem;   // [128][136]
    for (int jj = 0; jj < 4; ++jj){
      int colL = wn * 64 + jj * 16 + l15;
      float bb = bias[n0 + colL];
      for (int i = 0; i < 4; ++i)
        for (int r = 0; r < 4; ++r){
          int rowL = wm * 64 + i * 16 + lh * 4 + r;
          Ct[colL][rowL] = f2b(acc[i][jj][r] + bb);
        }
    }
    __syncthreads();
    int b = m0 >> 13, s0 = m0 & 8191;
    for (int p = 0; p < 8; ++p){
      int rowC = p * 16 + (tid >> 4), seg = tid & 15;
      int4 vv = *(const int4*)&Ct[rowC][seg * 8];
      int ngl = n0 + rowC, h = ngl >> 6, d = ngl & 63;
      *(int4*)&VhT[(((size_t)b * H + h) * DH2 + d) * SLEN + s0 + seg * 8] = vv;
    }
  }
}

// ---------------- flash attention ----------------------------------------
// grid (S/128, B*H), 256 thr (4 waves), wave owns 32 q-rows. BK=128.
__global__ __launch_bounds__(256) void attn_kernel(
    const short* __restrict__ Qh, const short* __restrict__ Kh,
    const short* __restrict__ VhT, short* __restrict__ attn_out)
{
  __shared__ __align__(16) short Ks[128][72];    // pad 8: kill stride-128B conflicts
  __shared__ __align__(16) short Vs[64][136];
  __shared__ __align__(16) short Ps[128][136];

  int tid = threadIdx.x;
  int lane = tid & 63, w = tid >> 6;
  int l15 = lane & 15, lh = lane >> 4;
  int bh = blockIdx.y;
  int q0 = blockIdx.x * 128;

  const short* Qbase = Qh + (size_t)bh * SLEN * DH2;
  const short* Kbase = Kh + (size_t)bh * SLEN * DH2;
  const short* Vbase = VhT + (size_t)bh * DH2 * SLEN;

  bf16x8 qf[2][2];
  for (int m = 0; m < 2; ++m)
    for (int kk = 0; kk < 2; ++kk)
      qf[m][kk] = *(const bf16x8*)(Qbase + (size_t)(q0 + w * 32 + m * 16 + l15) * DH2 + kk * 32 + lh * 8);

  f32x4 O[2][4];
  for (int m = 0; m < 2; ++m)
    for (int n = 0; n < 4; ++n)
      O[m][n] = (f32x4){0.f, 0.f, 0.f, 0.f};
  float mst[2][4], lst[2][4];
  for (int m = 0; m < 2; ++m)
    for (int r = 0; r < 4; ++r){ mst[m][r] = -INFINITY; lst[m][r] = 0.f; }

  for (int kt = 0; kt < SLEN / 128; ++kt){
    for (int j = 0; j < 4; ++j){                     // stage K tile 128x64
      int idx = j * 256 + tid;
      int r = idx >> 3, seg = idx & 7;
      *(int4*)&Ks[r][seg * 8] = *(const int4*)(Kbase + (size_t)(kt * 128 + r) * DH2 + seg * 8);
    }
    for (int j = 0; j < 4; ++j){                     // stage V^T tile 64x128
      int idx = j * 256 + tid;
      int d = idx >> 4, seg = idx & 15;
      *(int4*)&Vs[d][seg * 8] = *(const int4*)(Vbase + (size_t)d * SLEN + kt * 128 + seg * 8);
    }
    __syncthreads();

    f32x4 sacc[2][8];
    for (int m = 0; m < 2; ++m)
      for (int n = 0; n < 8; ++n)
        sacc[m][n] = (f32x4){0.f, 0.f, 0.f, 0.f};
    for (int kk = 0; kk < 2; ++kk)
      for (int n = 0; n < 8; ++n){
        bf16x8 bfv = *(const bf16x8*)&Ks[n * 16 + l15][kk * 32 + lh * 8];
        sacc[0][n] = MFMA16(qf[0][kk], bfv, sacc[0][n]);
        sacc[1][n] = MFMA16(qf[1][kk], bfv, sacc[1][n]);
      }

    // online softmax (rows live in 16-lane groups; butterfly over l15)
    for (int m = 0; m < 2; ++m)
      for (int r = 0; r < 4; ++r){
        float mx = sacc[m][0][r];
        for (int n = 1; n < 8; ++n) mx = fmaxf(mx, sacc[m][n][r]);
        mx = fmaxf(mx, __shfl_xor(mx, 1));
        mx = fmaxf(mx, __shfl_xor(mx, 2));
        mx = fmaxf(mx, __shfl_xor(mx, 4));
        mx = fmaxf(mx, __shfl_xor(mx, 8));
        float mold = mst[m][r];
        float mnew = fmaxf(mold, mx);
        float corr = __expf(mold - mnew);
        float rs = 0.f;
        for (int n = 0; n < 8; ++n){
          float p = __expf(sacc[m][n][r] - mnew);
          sacc[m][n][r] = p;
          rs += p;
        }
        rs += __shfl_xor(rs, 1);
        rs += __shfl_xor(rs, 2);
        rs += __shfl_xor(rs, 4);
        rs += __shfl_xor(rs, 8);
        lst[m][r] = lst[m][r] * corr + rs;
        mst[m][r] = mnew;
        for (int nn = 0; nn < 4; ++nn) O[m][nn][r] *= corr;
      }

    // P -> LDS (wave-private rows; no barrier needed before PV)
    for (int m = 0; m < 2; ++m)
      for (int n = 0; n < 8; ++n)
        for (int r = 0; r < 4; ++r)
          Ps[w * 32 + m * 16 + lh * 4 + r][n * 16 + l15] = f2b(sacc[m][n][r]);

    for (int k2 = 0; k2 < 4; ++k2){
      bf16x8 pa0 = *(const bf16x8*)&Ps[w * 32 + l15][k2 * 32 + lh * 8];
      bf16x8 pa1 = *(const bf16x8*)&Ps[w * 32 + 16 + l15][k2 * 32 + lh * 8];
      for (int nn = 0; nn < 4; ++nn){
        bf16x8 vb = *(const bf16x8*)&Vs[nn * 16 + l15][k2 * 32 + lh * 8];
        O[0][nn] = MFMA16(pa0, vb, O[0][nn]);
        O[1][nn] = MFMA16(pa1, vb, O[1][nn]);
      }
    }
    __syncthreads();
  }

  int b = bh >> 4, h = bh & 15;
  for (int m = 0; m < 2; ++m)
    for (int r = 0; r < 4; ++r){
      float inv = 1.0f / lst[m][r];
      int row = q0 + w * 32 + m * 16 + lh * 4 + r;
      for (int nn = 0; nn < 4; ++nn){
        int col = h * 64 + nn * 16 + l15;
        attn_out[((size_t)b * SLEN + row) * Dm + col] = f2b(O[m][nn][r] * inv);
      }
    }
}

// ---------------- output projection ---------------------------------------
__global__ __launch_bounds__(256) void oproj_kernel(
    const short* __restrict__ Aattn, const short* __restrict__ WoT,
    const float* __restrict__ bo, float* __restrict__ out)
{
  __shared__ __align__(16) char smem[32768];
  short* As = (short*)smem;                 // [128][64] linear
  short* Bs = (short*)(smem + 16384);

  int tid = threadIdx.x;
  int lane = tid & 63, w = tid >> 6;
  int l15 = lane & 15, lh = lane >> 4;
  int wm = w >> 1, wn = w & 1;
  int m0 = blockIdx.x * 128, n0 = blockIdx.y * 128;

  f32x4 acc[4][4];
  for (int i = 0; i < 4; ++i)
    for (int j = 0; j < 4; ++j)
      acc[i][j] = (f32x4){0.f, 0.f, 0.f, 0.f};

  for (int ko = 0; ko < 16; ++ko){
    for (int j = 0; j < 4; ++j){
      int c = w * 4 + j;
      int row = c * 8 + (lane >> 3), seg = lane & 7;
      gload16(Aattn + (size_t)(m0 + row) * Dm + ko * 64 + seg * 8, As + c * 512);
      gload16(WoT   + (size_t)(n0 + row) * Dm + ko * 64 + seg * 8, Bs + c * 512);
    }
    __syncthreads();
    for (int kk = 0; kk < 2; ++kk){
      bf16x8 af[4];
      for (int i = 0; i < 4; ++i)
        af[i] = *(const bf16x8*)(As + (size_t)(wm * 64 + i * 16 + l15) * 64 + kk * 32 + lh * 8);
      for (int jj = 0; jj < 4; ++jj){
        bf16x8 bfv = *(const bf16x8*)(Bs + (size_t)(wn * 64 + jj * 16 + l15) * 64 + kk * 32 + lh * 8);
        for (int i = 0; i < 4; ++i)
          acc[i][jj] = MFMA16(af[i], bfv, acc[i][jj]);
      }
    }
    __syncthreads();
  }
  for (int jj = 0; jj < 4; ++jj){
    int col = n0 + wn * 64 + jj * 16 + l15;
    float bb = bo[col];
    for (int i = 0; i < 4; ++i)
      for (int r = 0; r < 4; ++r){
        int row = m0 + wm * 64 + i * 16 + lh * 4 + r;
        out[(size_t)row * Dm + col] = acc[i][jj][r] + bb;
      }
  }
}

extern "C" void kernel_launch(void* const* d_in, const int* in_sizes, int n_in,
                              void* d_out, int out_size, void* d_ws, size_t ws_size,
                              hipStream_t stream)
{
  const float* v  = (const float*)d_in[0];
  const float* k  = (const float*)d_in[1];
  const float* q  = (const float*)d_in[2];
  const float* Wq = (const float*)d_in[3];
  const float* bq = (const float*)d_in[4];
  const float* Wk = (const float*)d_in[5];
  const float* bk = (const float*)d_in[6];
  const float* Wv = (const float*)d_in[7];
  const float* bv = (const float*)d_in[8];
  const float* Wo = (const float*)d_in[9];
  const float* bo = (const float*)d_in[10];
  float* out = (float*)d_out;

  char* ws = (char*)d_ws;
  const size_t MB = 1u << 20;
  short* WqT = (short*)(ws + 0 * MB);
  short* WkT = (short*)(ws + 2 * MB);
  short* WvT = (short*)(ws + 4 * MB);
  short* WoT = (short*)(ws + 6 * MB);
  short* Qh  = (short*)(ws + 8 * MB);     // [B][H][S][64] bf16, Q pre-scaled
  short* Kh  = (short*)(ws + 40 * MB);    // [B][H][S][64]
  short* VhT = (short*)(ws + 72 * MB);    // [B][H][64][S]
  short* Ao  = (short*)(ws + 104 * MB);   // [B*S][1024] bf16

  transpose_w_kernel<<<dim3(32, 32, 4), 256, 0, stream>>>(Wq, Wk, Wv, Wo, WqT, WkT, WvT, WoT);
  proj_kernel<<<dim3(128, 8, 3), 256, 0, stream>>>(q, k, v, WqT, WkT, WvT, bq, bk, bv, Qh, Kh, VhT);
  attn_kernel<<<dim3(64, 32), 256, 0, stream>>>(Qh, Kh, VhT, Ao);
  oproj_kernel<<<dim3(128, 8), 256, 0, stream>>>(Ao, WoT, bo, out);
}

// Round 3
// 1335.119 us; speedup vs baseline: 1.5864x; 1.5864x over previous
//
#include <hip/hip_runtime.h>
#include <math.h>
#include <stdint.h>

#define H 16
#define Dm 1024
#define DH2 64
#define SLEN 8192
#define BATCH 2
#define KVBLK 64

typedef __attribute__((ext_vector_type(8))) short bf16x8;
typedef __attribute__((ext_vector_type(4))) float f32x4;
typedef __attribute__((ext_vector_type(16))) float f32x16;
typedef __attribute__((ext_vector_type(4))) short short4v;
typedef __attribute__((ext_vector_type(4))) unsigned int uint4v;

#define MFMA16(a,b,c) __builtin_amdgcn_mfma_f32_16x16x32_bf16(a,b,c,0,0,0)
#define MFMA32(a,b,c) __builtin_amdgcn_mfma_f32_32x32x16_bf16(a,b,c,0,0,0)

static __device__ __forceinline__ short f2b(float f){
  unsigned u = __builtin_bit_cast(unsigned, f);
  u += 0x7fffu + ((u >> 16) & 1u);
  return (short)(u >> 16);
}

static __device__ __forceinline__ unsigned pack2(float lo, float hi){
  return (unsigned)(unsigned short)f2b(lo) | ((unsigned)(unsigned short)f2b(hi) << 16);
}

static __device__ __forceinline__ void gload16(const void* g, void* l){
  __builtin_amdgcn_global_load_lds((const __attribute__((address_space(1))) void*)g,
                                   (__attribute__((address_space(3))) void*)l, 16, 0, 0);
}

// ---------------- weight transpose: WT[n][k] = bf16(W[k][n]) ----------------
__global__ __launch_bounds__(256) void transpose_w_kernel(
    const float* __restrict__ Wq, const float* __restrict__ Wk,
    const float* __restrict__ Wv, const float* __restrict__ Wo,
    short* __restrict__ WqT, short* __restrict__ WkT,
    short* __restrict__ WvT, short* __restrict__ WoT)
{
  const float* W; short* WT;
  switch (blockIdx.z){
    case 0: W = Wq; WT = WqT; break;
    case 1: W = Wk; WT = WkT; break;
    case 2: W = Wv; WT = WvT; break;
    default: W = Wo; WT = WoT; break;
  }
  __shared__ float t[32][33];
  int tx = threadIdx.x & 31, ty = threadIdx.x >> 5;
  int x0 = blockIdx.x * 32, y0 = blockIdx.y * 32;
  for (int j = 0; j < 4; ++j){
    int r = ty + j * 8;
    t[r][tx] = W[(size_t)(y0 + r) * Dm + x0 + tx];
  }
  __syncthreads();
  for (int j = 0; j < 4; ++j){
    int r = ty + j * 8;
    WT[(size_t)(x0 + r) * Dm + y0 + tx] = f2b(t[tx][r]);
  }
}

// ---------------- QKV projection GEMM -------------------------------------
// z=0: Q (scaled 0.125*log2e) -> Qh[b][h][s][64]; z=1: K -> Kh; z=2: V -> VhT[b][h][64][s]
__global__ __launch_bounds__(256) void proj_kernel(
    const float* __restrict__ Aq, const float* __restrict__ Ak, const float* __restrict__ Av,
    const short* __restrict__ WqT, const short* __restrict__ WkT, const short* __restrict__ WvT,
    const float* __restrict__ bq, const float* __restrict__ bk, const float* __restrict__ bv,
    short* __restrict__ Qh, short* __restrict__ Kh, short* __restrict__ VhT)
{
  const float* A; const short* WT; const float* bias;
  int z = blockIdx.z;
  if (z == 0){ A = Aq; WT = WqT; bias = bq; }
  else if (z == 1){ A = Ak; WT = WkT; bias = bk; }
  else { A = Av; WT = WvT; bias = bv; }

  __shared__ __align__(16) char smem[34816];
  short (*As)[64] = (short(*)[64])smem;        // [128][64]
  short* Bs = (short*)(smem + 16384);          // [128][64] linear (gload_lds dest)

  int tid = threadIdx.x;
  int lane = tid & 63, w = tid >> 6;
  int l15 = lane & 15, lh = lane >> 4;
  int wm = w >> 1, wn = w & 1;
  int m0 = blockIdx.x * 128, n0 = blockIdx.y * 128;

  f32x4 acc[4][4];
  for (int i = 0; i < 4; ++i)
    for (int j = 0; j < 4; ++j)
      acc[i][j] = (f32x4){0.f, 0.f, 0.f, 0.f};

  for (int ko = 0; ko < 16; ++ko){
    for (int j = 0; j < 8; ++j){
      int idx = j * 256 + tid;
      int r = idx >> 4, c4 = idx & 15;
      float4 a = *(const float4*)(A + (size_t)(m0 + r) * Dm + ko * 64 + c4 * 4);
      short4v p; p[0] = f2b(a.x); p[1] = f2b(a.y); p[2] = f2b(a.z); p[3] = f2b(a.w);
      *(short4v*)&As[r][c4 * 4] = p;
    }
    for (int j = 0; j < 4; ++j){
      int c = w * 4 + j;
      int row = c * 8 + (lane >> 3), seg = lane & 7;
      gload16(WT + (size_t)(n0 + row) * Dm + ko * 64 + seg * 8, Bs + c * 512);
    }
    __syncthreads();
    for (int kk = 0; kk < 2; ++kk){
      bf16x8 af[4];
      for (int i = 0; i < 4; ++i)
        af[i] = *(const bf16x8*)&As[wm * 64 + i * 16 + l15][kk * 32 + lh * 8];
      for (int jj = 0; jj < 4; ++jj){
        bf16x8 bfv = *(const bf16x8*)(Bs + (size_t)(wn * 64 + jj * 16 + l15) * 64 + kk * 32 + lh * 8);
        for (int i = 0; i < 4; ++i)
          acc[i][jj] = MFMA16(af[i], bfv, acc[i][jj]);
      }
    }
    __syncthreads();
  }

  if (z < 2){
    short* out = (z == 0) ? Qh : Kh;
    // fold 1/sqrt(64) and log2(e) into Q so softmax uses exp2 directly
    float scale = (z == 0) ? 0.18033688011112042f : 1.0f;
    for (int jj = 0; jj < 4; ++jj){
      int col = n0 + wn * 64 + jj * 16 + l15;
      float bb = bias[col];
      int h = col >> 6, d = col & 63;
      for (int i = 0; i < 4; ++i)
        for (int r = 0; r < 4; ++r){
          int row = m0 + wm * 64 + i * 16 + lh * 4 + r;
          int b = row >> 13, s = row & 8191;
          out[(((size_t)b * H + h) * SLEN + s) * DH2 + d] = f2b((acc[i][jj][r] + bb) * scale);
        }
    }
  } else {
    short (*Ct)[136] = (short(*)[136])smem;   // [128][136]
    for (int jj = 0; jj < 4; ++jj){
      int colL = wn * 64 + jj * 16 + l15;
      float bb = bias[n0 + colL];
      for (int i = 0; i < 4; ++i)
        for (int r = 0; r < 4; ++r){
          int rowL = wm * 64 + i * 16 + lh * 4 + r;
          Ct[colL][rowL] = f2b(acc[i][jj][r] + bb);
        }
    }
    __syncthreads();
    int b = m0 >> 13, s0 = m0 & 8191;
    for (int p = 0; p < 8; ++p){
      int rowC = p * 16 + (tid >> 4), seg = tid & 15;
      int4 vv = *(const int4*)&Ct[rowC][seg * 8];
      int ngl = n0 + rowC, h = ngl >> 6, d = ngl & 63;
      *(int4*)&VhT[(((size_t)b * H + h) * DH2 + d) * SLEN + s0 + seg * 8] = vv;
    }
  }
}

// builds PV A-frag (one 16-k step) from 8 P regs S[b..b+7]; pairs lanes hi=0/1
#define MKFRAG(dst, S, b) { \
  unsigned p0 = pack2(S[b+0], S[b+1]), p1 = pack2(S[b+2], S[b+3]); \
  unsigned p2 = pack2(S[b+4], S[b+5]), p3 = pack2(S[b+6], S[b+7]); \
  unsigned s0 = (unsigned)__shfl_xor((int)p0, 32), s1 = (unsigned)__shfl_xor((int)p1, 32); \
  unsigned s2 = (unsigned)__shfl_xor((int)p2, 32), s3 = (unsigned)__shfl_xor((int)p3, 32); \
  uint4v u = hib ? (uint4v){s2, s3, p2, p3} : (uint4v){p0, p1, s0, s1}; \
  dst = __builtin_bit_cast(bf16x8, u); }

// ---------------- flash attention (8-wave, 32x32 swapped QK^T) -------------
// grid (S/256, B*H), 512 thr. Wave owns 32 q-rows. KVBLK=64, double-buffered.
// S^T = K.Q^T via mfma(K,Q): lane owns P-row q=lane&31 (32 of 64 k-slots;
// partner lane+32 has the rest). Softmax in-register, classic exact online
// rescale (skip only when no row max grows). P packed via f2b (RNE).
__global__ __launch_bounds__(512, 2) void attn_kernel(
    const short* __restrict__ Qh, const short* __restrict__ Kh,
    const short* __restrict__ VhT, short* __restrict__ attn_out)
{
  __shared__ __align__(16) short Ktile[2][4096];   // [64 k][64 d], chunk-XOR swizzled
  __shared__ __align__(16) short Vtile[2][4096];   // [64 d][64 k], chunk-XOR swizzled
  __shared__ float redbuf[8][32];                  // per-wave broadcast row

  const int tid = threadIdx.x;
  const int lane = tid & 63;
  const int w = tid >> 6;
  const int l31 = lane & 31;
  const int hi = lane >> 5;
  const bool hib = (hi != 0);
  const int bh = blockIdx.y;
  const int q0 = blockIdx.x * 256 + w * 32;

  const short* Qbase = Qh + ((size_t)bh * SLEN + q0) * DH2;
  const short* Kbase = Kh + (size_t)bh * SLEN * DH2;
  const short* Vbase = VhT + (size_t)bh * DH2 * SLEN;

  // Q regs: qf[ds] = Q[q0+l31][ds*16 + hi*8 ..+8]  (B-frag of mfma(K,Q))
  bf16x8 qf[4];
#pragma unroll
  for (int ds = 0; ds < 4; ++ds)
    qf[ds] = *(const bf16x8*)(Qbase + (size_t)l31 * DH2 + ds * 16 + hi * 8);

  f32x16 Oa0, Oa1;
#pragma unroll
  for (int i = 0; i < 16; ++i){ Oa0[i] = 0.f; Oa1[i] = 0.f; }
  float m_run = -INFINITY, l_run = 0.f;

  // loop-invariant LDS read offsets (shorts)
  int koff[4];
#pragma unroll
  for (int ds = 0; ds < 4; ++ds)
    koff[ds] = l31 * 64 + (((ds * 2 + hi) ^ (l31 & 7)) * 8);
  int voff[2][4];
#pragma unroll
  for (int n = 0; n < 2; ++n)
#pragma unroll
    for (int st = 0; st < 4; ++st)
      voff[n][st] = (n * 32 + l31) * 64 + (((st * 2 + hi) ^ (l31 & 7)) * 8);

  // staging: each thread 1 K-chunk + 1 V-chunk (16B) per tile.
  // Source address pre-XOR-swizzled so linear gload_lds dest yields swizzled tile.
  const short* spK = Kbase + (size_t)(tid >> 3) * DH2 + (((tid & 7) ^ ((tid >> 3) & 7)) * 8);
  const short* spV = Vbase + (size_t)(tid >> 3) * SLEN + (((tid & 7) ^ ((tid >> 3) & 7)) * 8);
  short* dK0 = Ktile[0] + tid * 8; short* dK1 = Ktile[1] + tid * 8;
  short* dV0 = Vtile[0] + tid * 8; short* dV1 = Vtile[1] + tid * 8;

  gload16(spK, dK0); gload16(spV, dV0);       // prologue: tile 0 -> buf 0
  spK += (size_t)KVBLK * DH2; spV += KVBLK;

  for (int kt = 0; kt < SLEN / KVBLK; ++kt){
    __syncthreads();                          // buf[kt&1] staged; other buf free
    const short* Kt = (kt & 1) ? Ktile[1] : Ktile[0];
    const short* Vt = (kt & 1) ? Vtile[1] : Vtile[0];
    if (kt + 1 < SLEN / KVBLK){
      gload16(spK, (kt & 1) ? dK0 : dK1);
      gload16(spV, (kt & 1) ? dV0 : dV1);
      spK += (size_t)KVBLK * DH2; spV += KVBLK;
    }

    // ---- QK^T (swapped): sa0[r]=S[ki=crow(r,hi)][q=l31], sa1: ki+32 ----
    f32x16 sa0, sa1;
#pragma unroll
    for (int i = 0; i < 16; ++i){ sa0[i] = 0.f; sa1[i] = 0.f; }
#pragma unroll
    for (int ds = 0; ds < 4; ++ds){
      bf16x8 kf0 = *(const bf16x8*)(Kt + koff[ds]);
      bf16x8 kf1 = *(const bf16x8*)(Kt + koff[ds] + 32 * 64);
      sa0 = MFMA32(kf0, qf[ds], sa0);
      sa1 = MFMA32(kf1, qf[ds], sa1);
    }

    // ---- row max (32 in-lane + partner) ----
    float m0 = fmaxf(fmaxf(sa0[0], sa0[1]), fmaxf(sa0[2], sa0[3]));
    float m1 = fmaxf(fmaxf(sa0[4], sa0[5]), fmaxf(sa0[6], sa0[7]));
    float m2 = fmaxf(fmaxf(sa0[8], sa0[9]), fmaxf(sa0[10], sa0[11]));
    float m3 = fmaxf(fmaxf(sa0[12], sa0[13]), fmaxf(sa0[14], sa0[15]));
    float m4 = fmaxf(fmaxf(sa1[0], sa1[1]), fmaxf(sa1[2], sa1[3]));
    float m5 = fmaxf(fmaxf(sa1[4], sa1[5]), fmaxf(sa1[6], sa1[7]));
    float m6 = fmaxf(fmaxf(sa1[8], sa1[9]), fmaxf(sa1[10], sa1[11]));
    float m7 = fmaxf(fmaxf(sa1[12], sa1[13]), fmaxf(sa1[14], sa1[15]));
    float pmax = fmaxf(fmaxf(fmaxf(m0, m1), fmaxf(m2, m3)),
                       fmaxf(fmaxf(m4, m5), fmaxf(m6, m7)));
    pmax = fmaxf(pmax, __shfl_xor(pmax, 32));

    // ---- exact online rescale (skip only if no row max grew) ----
    if (__any(pmax > m_run)){
      float m_new = fmaxf(m_run, pmax);
      float corr = __builtin_exp2f(m_run - m_new);
      l_run *= corr;
      m_run = m_new;
      redbuf[w][l31] = corr;                  // wave-private row; in-order LDS
#pragma unroll
      for (int j = 0; j < 4; ++j){
        f32x4 cr = *(const f32x4*)&redbuf[w][j * 8 + hi * 4];  // qi = 8j+4hi+i
#pragma unroll
        for (int i = 0; i < 4; ++i){
          Oa0[j * 4 + i] *= cr[i];
          Oa1[j * 4 + i] *= cr[i];
        }
      }
    }

    float rs = 0.f;
#pragma unroll
    for (int i = 0; i < 16; ++i){
      float p0 = __builtin_exp2f(sa0[i] - m_run);
      float p1 = __builtin_exp2f(sa1[i] - m_run);
      sa0[i] = p0; sa1[i] = p1;
      rs += p0 + p1;
    }
    rs += __shfl_xor(rs, 32);
    l_run += rs;

    // ---- pack P to bf16 PV A-frags (in-register, RNE via f2b) ----
    bf16x8 pa0, pa1, pa2, pa3;
    MKFRAG(pa0, sa0, 0); MKFRAG(pa1, sa0, 8);
    MKFRAG(pa2, sa1, 0); MKFRAG(pa3, sa1, 8);

    // ---- PV: O[q][d] += P.V ----
    bf16x8 vb;
    vb = *(const bf16x8*)(Vt + voff[0][0]); Oa0 = MFMA32(pa0, vb, Oa0);
    vb = *(const bf16x8*)(Vt + voff[1][0]); Oa1 = MFMA32(pa0, vb, Oa1);
    vb = *(const bf16x8*)(Vt + voff[0][1]); Oa0 = MFMA32(pa1, vb, Oa0);
    vb = *(const bf16x8*)(Vt + voff[1][1]); Oa1 = MFMA32(pa1, vb, Oa1);
    vb = *(const bf16x8*)(Vt + voff[0][2]); Oa0 = MFMA32(pa2, vb, Oa0);
    vb = *(const bf16x8*)(Vt + voff[1][2]); Oa1 = MFMA32(pa2, vb, Oa1);
    vb = *(const bf16x8*)(Vt + voff[0][3]); Oa0 = MFMA32(pa3, vb, Oa0);
    vb = *(const bf16x8*)(Vt + voff[1][3]); Oa1 = MFMA32(pa3, vb, Oa1);
  }

  // ---- epilogue: O / l, store bf16 ----
  float inv = 1.0f / l_run;
  redbuf[w][l31] = inv;
  int b = bh >> 4, h = bh & 15;
#pragma unroll
  for (int j = 0; j < 4; ++j){
    f32x4 iv = *(const f32x4*)&redbuf[w][j * 8 + hi * 4];
#pragma unroll
    for (int i = 0; i < 4; ++i){
      int qi = j * 8 + hi * 4 + i;
      size_t rowoff = ((size_t)b * SLEN + q0 + qi) * Dm + h * 64;
      attn_out[rowoff + l31]      = f2b(Oa0[j * 4 + i] * iv[i]);
      attn_out[rowoff + 32 + l31] = f2b(Oa1[j * 4 + i] * iv[i]);
    }
  }
}

// ---------------- output projection ---------------------------------------
__global__ __launch_bounds__(256) void oproj_kernel(
    const short* __restrict__ Aattn, const short* __restrict__ WoT,
    const float* __restrict__ bo, float* __restrict__ out)
{
  __shared__ __align__(16) char smem[32768];
  short* As = (short*)smem;
  short* Bs = (short*)(smem + 16384);

  int tid = threadIdx.x;
  int lane = tid & 63, w = tid >> 6;
  int l15 = lane & 15, lh = lane >> 4;
  int wm = w >> 1, wn = w & 1;
  int m0 = blockIdx.x * 128, n0 = blockIdx.y * 128;

  f32x4 acc[4][4];
  for (int i = 0; i < 4; ++i)
    for (int j = 0; j < 4; ++j)
      acc[i][j] = (f32x4){0.f, 0.f, 0.f, 0.f};

  for (int ko = 0; ko < 16; ++ko){
    for (int j = 0; j < 4; ++j){
      int c = w * 4 + j;
      int row = c * 8 + (lane >> 3), seg = lane & 7;
      gload16(Aattn + (size_t)(m0 + row) * Dm + ko * 64 + seg * 8, As + c * 512);
      gload16(WoT   + (size_t)(n0 + row) * Dm + ko * 64 + seg * 8, Bs + c * 512);
    }
    __syncthreads();
    for (int kk = 0; kk < 2; ++kk){
      bf16x8 af[4];
      for (int i = 0; i < 4; ++i)
        af[i] = *(const bf16x8*)(As + (size_t)(wm * 64 + i * 16 + l15) * 64 + kk * 32 + lh * 8);
      for (int jj = 0; jj < 4; ++jj){
        bf16x8 bfv = *(const bf16x8*)(Bs + (size_t)(wn * 64 + jj * 16 + l15) * 64 + kk * 32 + lh * 8);
        for (int i = 0; i < 4; ++i)
          acc[i][jj] = MFMA16(af[i], bfv, acc[i][jj]);
      }
    }
    __syncthreads();
  }
  for (int jj = 0; jj < 4; ++jj){
    int col = n0 + wn * 64 + jj * 16 + l15;
    float bb = bo[col];
    for (int i = 0; i < 4; ++i)
      for (int r = 0; r < 4; ++r){
        int row = m0 + wm * 64 + i * 16 + lh * 4 + r;
        out[(size_t)row * Dm + col] = acc[i][jj][r] + bb;
      }
  }
}

extern "C" void kernel_launch(void* const* d_in, const int* in_sizes, int n_in,
                              void* d_out, int out_size, void* d_ws, size_t ws_size,
                              hipStream_t stream)
{
  const float* v  = (const float*)d_in[0];
  const float* k  = (const float*)d_in[1];
  const float* q  = (const float*)d_in[2];
  const float* Wq = (const float*)d_in[3];
  const float* bq = (const float*)d_in[4];
  const float* Wk = (const float*)d_in[5];
  const float* bk = (const float*)d_in[6];
  const float* Wv = (const float*)d_in[7];
  const float* bv = (const float*)d_in[8];
  const float* Wo = (const float*)d_in[9];
  const float* bo = (const float*)d_in[10];
  float* out = (float*)d_out;

  char* ws = (char*)d_ws;
  const size_t MB = 1u << 20;
  short* WqT = (short*)(ws + 0 * MB);
  short* WkT = (short*)(ws + 2 * MB);
  short* WvT = (short*)(ws + 4 * MB);
  short* WoT = (short*)(ws + 6 * MB);
  short* Qh  = (short*)(ws + 8 * MB);     // [B][H][S][64] bf16, Q pre-scaled by 0.125*log2e
  short* Kh  = (short*)(ws + 40 * MB);    // [B][H][S][64]
  short* VhT = (short*)(ws + 72 * MB);    // [B][H][64][S]
  short* Ao  = (short*)(ws + 104 * MB);   // [B*S][1024] bf16

  transpose_w_kernel<<<dim3(32, 32, 4), 256, 0, stream>>>(Wq, Wk, Wv, Wo, WqT, WkT, WvT, WoT);
  proj_kernel<<<dim3(128, 8, 3), 256, 0, stream>>>(q, k, v, WqT, WkT, WvT, bq, bk, bv, Qh, Kh, VhT);
  attn_kernel<<<dim3(32, 32), 512, 0, stream>>>(Qh, Kh, VhT, Ao);
  oproj_kernel<<<dim3(128, 8), 256, 0, stream>>>(Ao, WoT, bo, out);
}